// Round 10
// baseline (93.060 us; speedup 1.0000x reference)
//
#include <hip/hip_runtime.h>
#include <math.h>

// BoundaryDistanceLoss — H=W=1024 binary masks (float 0/1).
// edges = seg - erode3x3(seg); exact EDT of edges; loss =
// sigmoid((mean(target_edges*pred_dt) + mean(pred_edges*target_dt))/2).
//
// R9->R10: fused row-pass INTO the column kernel by redundant windowed
// recompute (NO cross-block sync — both sync-based fusions failed/regressed).
// Each block ballots seg bits for its 144-row x 64-col window into LDS u64
// masks, derives edges via bit ops, extracts per-col row-distance g with
// clz/ffs. Windowed g overestimates; exact iff D2 <= min(576, dl^2, dr^2)
// (missed col-candidates are >=24 away); else statistically-dead global
// brute-force fallback (also reproduces empty-row/empty-image ref semantics).
// 2 nodes: k_main (1024 blocks) + k_fin. No atomics, no fences.
//
// ws layout: partial (4KB f32) only.

#define HW 1024
#define WIN 8
#define RPB 128
#define KROWS (RPB + 2 * WIN)   // 144
#define HS_STRIDE 17

// edge test straight from global seg (fallback only; zero-pad semantics)
__device__ inline int edge_at(const float* __restrict__ seg, int k, int j)
{
    if ((unsigned)k >= (unsigned)HW || (unsigned)j >= (unsigned)HW) return 0;
    if (seg[k * HW + j] == 0.f) return 0;
    bool all9 = true;
    #pragma unroll
    for (int dy = -1; dy <= 1; ++dy)
        #pragma unroll
        for (int dx = -1; dx <= 1; ++dx) {
            const int kk = k + dy, jj = j + dx;
            const float v = ((unsigned)kk < (unsigned)HW && (unsigned)jj < (unsigned)HW)
                            ? seg[kk * HW + jj] : 0.f;
            all9 = all9 && (v != 0.f);
        }
    return all9 ? 0 : 1;
}

// ------------- Fused kernel: windowed row-pass + column EDT + partial -------
// grid (64 col-tiles, 8 row-chunks, 2 images) = 1024 blocks, block 256.
__global__ __launch_bounds__(256)
void k_main(const float* __restrict__ pred, const float* __restrict__ targ,
            float* __restrict__ partial)
{
    const int t    = threadIdx.x;
    const int lane = t & 63;
    const int wv   = t >> 6;
    const int j0 = blockIdx.x * 16;
    const int i0 = blockIdx.y * RPB;
    const int mc = blockIdx.z;
    const float* __restrict__ segc = mc ? targ : pred;   // image whose DT we take
    const float* __restrict__ segw = mc ? pred : targ;   // OTHER image (weights)

    __shared__ unsigned long long s_mc[146];  // segc rows [i0-9, i0+137)
    __shared__ unsigned long long s_me[130];  // segw rows [i0-1, i0+129)
    __shared__ float hs[KROWS * HS_STRIDE];
    __shared__ unsigned short esb[RPB];
    __shared__ float wsum[4];

    // 64-col window: lane covers col W0+lane; tile cols at bits 24..39
    const int W0 = j0 - 24;
    const int colc = W0 + lane;
    const bool colok = (unsigned)colc < (unsigned)HW;

    // Phase 1: ballot-stage segc bits (coalesced 256B/row)
    for (int ss = wv; ss < 146; ss += 4) {
        const int rr = i0 - 9 + ss;
        unsigned long long m = 0ull;
        if ((unsigned)rr < (unsigned)HW) {
            const float v = colok ? segc[rr * HW + colc] : 0.f;
            m = __ballot(v != 0.f);
        }
        if (lane == 0) s_mc[ss] = m;
    }
    // Phase 2: ballot-stage segw bits
    for (int ss = wv; ss < 130; ss += 4) {
        const int rr = i0 - 1 + ss;
        unsigned long long m = 0ull;
        if ((unsigned)rr < (unsigned)HW) {
            const float v = colok ? segw[rr * HW + colc] : 0.f;
            m = __ballot(v != 0.f);
        }
        if (lane == 0) s_me[ss] = m;
    }
    __syncthreads();

    // Phase 3: windowed row-pass -> h = g^2 + k^2 into hs (threads 0..143)
    if (t < KROWS) {
        const int kr = i0 - WIN + t;            // edge row for hs row t
        if ((unsigned)kr < (unsigned)HW) {
            const unsigned long long sA = s_mc[t], sB = s_mc[t + 1], sC = s_mc[t + 2];
            const unsigned long long va = sA & sB & sC;
            const unsigned long long er = va & (va << 1) & (va >> 1);
            // erosion valid only for bits 1..62 (need both col neighbors)
            const unsigned long long edge = (sB & ~er) & 0x7FFFFFFFFFFFFFFEull;
            const float krk = (float)(kr * kr);
            #pragma unroll
            for (int jc = 0; jc < 16; ++jc) {
                const int p = 24 + jc;
                const unsigned long long mle = edge & ((1ull << (p + 1)) - 1ull);
                const unsigned long long mge = edge >> p;
                int g = 1 << 20;
                if (mle) g = p - (63 - __clzll((long long)mle));
                if (mge) g = min(g, __ffsll((unsigned long long)mge) - 1);
                hs[t * HS_STRIDE + jc] = (g < (1 << 20))
                    ? fmaf((float)g, (float)g, krk) : 1e30f;
            }
        } else {
            #pragma unroll
            for (int jc = 0; jc < 16; ++jc)
                hs[t * HS_STRIDE + jc] = 1e30f;
        }
    }
    // Phase 4: weight edge bits for rows [i0, i0+128) (threads 0..127)
    if (t < RPB) {
        const unsigned long long sA = s_me[t], sB = s_me[t + 1], sC = s_me[t + 2];
        const unsigned long long va = sA & sB & sC;
        const unsigned long long er = va & (va << 1) & (va >> 1);
        const unsigned long long edge = sB & ~er;   // bits 24..39 have valid neighbors
        esb[t] = (unsigned short)((edge >> 24) & 0xFFFFull);
    }
    __syncthreads();

    // Phase 5: column EDT (windowed, exact) + weighted sum
    const int jj = t & 15;
    const int iw = t >> 4;   // 0..15, each owns 8 rows
    float lsum = 0.f;

    #pragma unroll
    for (int g = 0; g < 2; ++g) {
        const int ib = i0 + iw * 8 + g * 4;      // 4 consecutive output rows
        const int kkS = iw * 8 + g * 4;          // = (ib-WIN) - (i0-WIN)
        float b0 = 3e38f, b1 = 3e38f, b2 = 3e38f, b3 = 3e38f;
        float kf = (float)(ib - WIN);
        const float m0 = -2.f * (float)(ib);
        const float m1 = -2.f * (float)(ib + 1);
        const float m2 = -2.f * (float)(ib + 2);
        const float m3 = -2.f * (float)(ib + 3);
        #pragma unroll
        for (int kk = kkS; kk < kkS + 2 * WIN + 4; ++kk) {
            const float hvv = hs[kk * HS_STRIDE + jj];
            b0 = fminf(b0, fmaf(m0, kf, hvv));
            b1 = fminf(b1, fmaf(m1, kf, hvv));
            b2 = fminf(b2, fmaf(m2, kf, hvv));
            b3 = fminf(b3, fmaf(m3, kf, hvv));
            kf += 1.f;
        }
        const int sLo = max(0, ib - WIN);
        const int sHi = min(HW - 1, ib + WIN + 3);
        float bs[4] = {b0, b1, b2, b3};
        #pragma unroll
        for (int w = 0; w < 4; ++w) {
            const int i = ib + w;
            float D2 = (float)(i * i) + bs[w];
            // exact iff no missed candidate can beat D2:
            //   col-window misses: dist^2 >= 24^2 = 576
            //   row-window misses: dist^2 >= dl^2 / dr^2
            const int dl = i - sLo + 1, dr = sHi + 1 - i;
            const bool need = (D2 > 576.f) ||
                              ((sLo > 0) && (D2 > (float)(dl * dl))) ||
                              ((sHi < HW - 1) && (D2 > (float)(dr * dr)));
            if (need) {  // statistically-dead exact fallback (global scan)
                const int jg = j0 + jj;
                float bb = 1e6f - (float)jg;     // empty-row/empty-image floor
                bb = bb * bb;
                for (int k = 0; k < HW; ++k) {
                    const float rowt = (float)((i - k) * (i - k));
                    if (rowt >= bb) continue;
                    for (int d = 0; d < HW; ++d) {
                        const float dd = rowt + (float)(d * d);
                        if (dd >= bb) break;
                        if (edge_at(segc, k, jg - d) || edge_at(segc, k, jg + d)) {
                            bb = dd; break;
                        }
                    }
                }
                D2 = bb;
            }
            const unsigned wbit = (esb[i - i0] >> jj) & 1u;
            lsum += wbit ? sqrtf(D2) : 0.f;
        }
    }

    // reduce: wave shuffle then cross-wave via LDS; ONE plain store per block
    #pragma unroll
    for (int off = 32; off > 0; off >>= 1) lsum += __shfl_down(lsum, off);
    if ((t & 63) == 0) wsum[t >> 6] = lsum;
    __syncthreads();
    if (t == 0) {
        const int bid = blockIdx.x + 64 * (blockIdx.y + 8 * blockIdx.z);
        partial[bid] = wsum[0] + wsum[1] + wsum[2] + wsum[3];
    }
}

// ---------------- Kernel C: reduce 1024 partials + sigmoid ----------------
__global__ __launch_bounds__(256)
void k_fin(const float* __restrict__ partial, float* __restrict__ out)
{
    const int t = threadIdx.x;
    float s = partial[t] + partial[t + 256] + partial[t + 512] + partial[t + 768];
    #pragma unroll
    for (int off = 32; off > 0; off >>= 1) s += __shfl_down(s, off);
    __shared__ float w[4];
    if ((t & 63) == 0) w[t >> 6] = s;
    __syncthreads();
    if (t == 0) {
        const float tot = w[0] + w[1] + w[2] + w[3];
        const float loss = tot * (1.f / (2.f * 1024.f * 1024.f));
        out[0] = 1.f / (1.f + expf(-loss));
    }
}

extern "C" void kernel_launch(void* const* d_in, const int* in_sizes, int n_in,
                              void* d_out, int out_size, void* d_ws, size_t ws_size,
                              hipStream_t stream)
{
    const float* preds   = (const float*)d_in[0];
    const float* targets = (const float*)d_in[1];
    float* out = (float*)d_out;

    float* partial = (float*)d_ws;   // 4 KB

    dim3 gM(HW / 16, HW / RPB, 2);
    k_main<<<gM, 256, 0, stream>>>(preds, targets, partial);

    k_fin<<<1, 256, 0, stream>>>(partial, out);
}

// Round 11
// 79.256 us; speedup vs baseline: 1.1742x; 1.1742x over previous
//
#include <hip/hip_runtime.h>
#include <math.h>

// BoundaryDistanceLoss — H=W=1024 binary masks (float 0/1).
// edges = seg - erode3x3(seg); exact EDT of edges; loss =
// sigmoid((mean(target_edges*pred_dt) + mean(pred_edges*target_dt))/2).
//
// R10->R11: same 2-node fused structure (windowed row-pass recompute inside
// the column kernel; logic proven absmax=0.0 in R10), staging REBUILT:
// R10's ballot loop was a serial load->ballot->lane0-store chain (k_main
// 41us, VALUBusy 24%, 1.2TB/s). Now: 256 threads issue independent float4
// loads (17 iters, full MLP, coalesced), nibble-ize, byte-store to LDS;
// then 276 threads pack 16 bytes -> u64 row masks with pure bit ops.
// No ballots, no cross-lane ops, no dependent chains.
//
// ws layout: partial (4KB f32) only.

#define HW 1024
#define WIN 8
#define RPB 128
#define KROWS (RPB + 2 * WIN)   // 144
#define HS_STRIDE 17
#define NC 146                  // segc rows staged: [i0-9, i0+137)
#define NW 130                  // segw rows staged: [i0-1, i0+129)
#define NBYTES ((NC + NW) * 16) // 4416

// edge test straight from global seg (fallback only; zero-pad semantics)
__device__ inline int edge_at(const float* __restrict__ seg, int k, int j)
{
    if ((unsigned)k >= (unsigned)HW || (unsigned)j >= (unsigned)HW) return 0;
    if (seg[k * HW + j] == 0.f) return 0;
    bool all9 = true;
    #pragma unroll
    for (int dy = -1; dy <= 1; ++dy)
        #pragma unroll
        for (int dx = -1; dx <= 1; ++dx) {
            const int kk = k + dy, jj = j + dx;
            const float v = ((unsigned)kk < (unsigned)HW && (unsigned)jj < (unsigned)HW)
                            ? seg[kk * HW + jj] : 0.f;
            all9 = all9 && (v != 0.f);
        }
    return all9 ? 0 : 1;
}

// ------------- Fused kernel: windowed row-pass + column EDT + partial -------
// grid (64 col-tiles, 8 row-chunks, 2 images) = 1024 blocks, block 256.
__global__ __launch_bounds__(256)
void k_main(const float* __restrict__ pred, const float* __restrict__ targ,
            float* __restrict__ partial)
{
    const int t  = threadIdx.x;
    const int j0 = blockIdx.x * 16;
    const int i0 = blockIdx.y * RPB;
    const int mc = blockIdx.z;
    const float* __restrict__ segc = mc ? targ : pred;   // image whose DT we take
    const float* __restrict__ segw = mc ? pred : targ;   // OTHER image (weights)

    __shared__ alignas(16) unsigned char sbytes[NBYTES];
    __shared__ unsigned long long s_mc[NC];
    __shared__ unsigned long long s_me[NW];
    __shared__ float hs[KROWS * HS_STRIDE];
    __shared__ unsigned short esb[RPB];
    __shared__ float wsum[4];

    // 64-col window: cols [W0, W0+64); tile cols at bits 24..39.
    // W0 = 16*bx - 24 is a multiple of 4 -> float4 chunks never straddle the
    // image border (fully in or fully out), and are 16B-aligned.
    const int W0 = j0 - 24;

    // Phase 1: stage seg bits as LDS nibble-bytes — independent float4 loads,
    // full memory-level parallelism, zero cross-lane ops.
    for (int idx = t; idx < NBYTES; idx += 256) {
        const int  isW = idx >= NC * 16;
        const int  rel = isW ? idx - NC * 16 : idx;
        const int  row = rel >> 4, c4 = rel & 15;
        const int  gr  = isW ? (i0 - 1 + row) : (i0 - 9 + row);
        const int  c   = W0 + c4 * 4;
        float4 v = make_float4(0.f, 0.f, 0.f, 0.f);
        if ((unsigned)gr < (unsigned)HW && (unsigned)c <= 1020u) {
            const float* __restrict__ base = isW ? segw : segc;
            v = *(const float4*)&base[gr * HW + c];
        }
        const unsigned by = (unsigned)(v.x != 0.f) | ((unsigned)(v.y != 0.f) << 1)
                          | ((unsigned)(v.z != 0.f) << 2) | ((unsigned)(v.w != 0.f) << 3);
        sbytes[idx] = (unsigned char)by;
    }
    __syncthreads();

    // Phase 2: pack each row's 16 nibble-bytes into one u64 mask (pure bit ops)
    for (int rowi = t; rowi < NC + NW; rowi += 256) {
        const uint4 u = *(const uint4*)&sbytes[rowi * 16];
        const unsigned wq[4] = {u.x, u.y, u.z, u.w};
        unsigned long long r = 0ull;
        #pragma unroll
        for (int q = 0; q < 4; ++q) {
            const unsigned x = wq[q] & 0x0F0F0F0Fu;
            const unsigned y = x | (x >> 4);
            const unsigned h16 = (y & 0xFFu) | (((y >> 16) & 0xFFu) << 8);
            r |= (unsigned long long)h16 << (16 * q);
        }
        if (rowi < NC) s_mc[rowi] = r;
        else           s_me[rowi - NC] = r;
    }
    __syncthreads();

    // Phase 3: windowed row-pass -> h = g^2 + k^2 into hs (threads 0..143)
    if (t < KROWS) {
        const int kr = i0 - WIN + t;            // edge row for hs row t
        if ((unsigned)kr < (unsigned)HW) {
            const unsigned long long sA = s_mc[t], sB = s_mc[t + 1], sC = s_mc[t + 2];
            const unsigned long long va = sA & sB & sC;
            const unsigned long long er = va & (va << 1) & (va >> 1);
            // erosion valid only for bits 1..62 (need both col neighbors)
            const unsigned long long edge = (sB & ~er) & 0x7FFFFFFFFFFFFFFEull;
            const float krk = (float)(kr * kr);
            #pragma unroll
            for (int jc = 0; jc < 16; ++jc) {
                const int p = 24 + jc;
                const unsigned long long mle = edge & ((1ull << (p + 1)) - 1ull);
                const unsigned long long mge = edge >> p;
                int g = 1 << 20;
                if (mle) g = p - (63 - __clzll((long long)mle));
                if (mge) g = min(g, __ffsll((unsigned long long)mge) - 1);
                hs[t * HS_STRIDE + jc] = (g < (1 << 20))
                    ? fmaf((float)g, (float)g, krk) : 1e30f;
            }
        } else {
            #pragma unroll
            for (int jc = 0; jc < 16; ++jc)
                hs[t * HS_STRIDE + jc] = 1e30f;
        }
    }
    // Phase 4: weight edge bits for rows [i0, i0+128) (threads 0..127)
    if (t < RPB) {
        const unsigned long long sA = s_me[t], sB = s_me[t + 1], sC = s_me[t + 2];
        const unsigned long long va = sA & sB & sC;
        const unsigned long long er = va & (va << 1) & (va >> 1);
        const unsigned long long edge = sB & ~er;   // bits 24..39 have valid neighbors
        esb[t] = (unsigned short)((edge >> 24) & 0xFFFFull);
    }
    __syncthreads();

    // Phase 5: column EDT (windowed, exact) + weighted sum
    const int jj = t & 15;
    const int iw = t >> 4;   // 0..15, each owns 8 rows
    float lsum = 0.f;

    #pragma unroll
    for (int g = 0; g < 2; ++g) {
        const int ib = i0 + iw * 8 + g * 4;      // 4 consecutive output rows
        const int kkS = iw * 8 + g * 4;          // = (ib-WIN) - (i0-WIN)
        float b0 = 3e38f, b1 = 3e38f, b2 = 3e38f, b3 = 3e38f;
        float kf = (float)(ib - WIN);
        const float m0 = -2.f * (float)(ib);
        const float m1 = -2.f * (float)(ib + 1);
        const float m2 = -2.f * (float)(ib + 2);
        const float m3 = -2.f * (float)(ib + 3);
        #pragma unroll
        for (int kk = kkS; kk < kkS + 2 * WIN + 4; ++kk) {
            const float hvv = hs[kk * HS_STRIDE + jj];
            b0 = fminf(b0, fmaf(m0, kf, hvv));
            b1 = fminf(b1, fmaf(m1, kf, hvv));
            b2 = fminf(b2, fmaf(m2, kf, hvv));
            b3 = fminf(b3, fmaf(m3, kf, hvv));
            kf += 1.f;
        }
        const int sLo = max(0, ib - WIN);
        const int sHi = min(HW - 1, ib + WIN + 3);
        float bs[4] = {b0, b1, b2, b3};
        #pragma unroll
        for (int w = 0; w < 4; ++w) {
            const int i = ib + w;
            float D2 = (float)(i * i) + bs[w];
            // exact iff no missed candidate can beat D2:
            //   col-window misses: dist^2 >= 24^2 = 576
            //   row-window misses: dist^2 >= dl^2 / dr^2
            const int dl = i - sLo + 1, dr = sHi + 1 - i;
            const bool need = (D2 > 576.f) ||
                              ((sLo > 0) && (D2 > (float)(dl * dl))) ||
                              ((sHi < HW - 1) && (D2 > (float)(dr * dr)));
            if (need) {  // statistically-dead exact fallback (global scan)
                const int jg = j0 + jj;
                float bb = 1e6f - (float)jg;     // empty-row/empty-image floor
                bb = bb * bb;
                for (int k = 0; k < HW; ++k) {
                    const float rowt = (float)((i - k) * (i - k));
                    if (rowt >= bb) continue;
                    for (int d = 0; d < HW; ++d) {
                        const float dd = rowt + (float)(d * d);
                        if (dd >= bb) break;
                        if (edge_at(segc, k, jg - d) || edge_at(segc, k, jg + d)) {
                            bb = dd; break;
                        }
                    }
                }
                D2 = bb;
            }
            const unsigned wbit = (esb[i - i0] >> jj) & 1u;
            lsum += wbit ? sqrtf(D2) : 0.f;
        }
    }

    // reduce: wave shuffle then cross-wave via LDS; ONE plain store per block
    #pragma unroll
    for (int off = 32; off > 0; off >>= 1) lsum += __shfl_down(lsum, off);
    if ((t & 63) == 0) wsum[t >> 6] = lsum;
    __syncthreads();
    if (t == 0) {
        const int bid = blockIdx.x + 64 * (blockIdx.y + 8 * blockIdx.z);
        partial[bid] = wsum[0] + wsum[1] + wsum[2] + wsum[3];
    }
}

// ---------------- Kernel C: reduce 1024 partials + sigmoid ----------------
__global__ __launch_bounds__(256)
void k_fin(const float* __restrict__ partial, float* __restrict__ out)
{
    const int t = threadIdx.x;
    float s = partial[t] + partial[t + 256] + partial[t + 512] + partial[t + 768];
    #pragma unroll
    for (int off = 32; off > 0; off >>= 1) s += __shfl_down(s, off);
    __shared__ float w[4];
    if ((t & 63) == 0) w[t >> 6] = s;
    __syncthreads();
    if (t == 0) {
        const float tot = w[0] + w[1] + w[2] + w[3];
        const float loss = tot * (1.f / (2.f * 1024.f * 1024.f));
        out[0] = 1.f / (1.f + expf(-loss));
    }
}

extern "C" void kernel_launch(void* const* d_in, const int* in_sizes, int n_in,
                              void* d_out, int out_size, void* d_ws, size_t ws_size,
                              hipStream_t stream)
{
    const float* preds   = (const float*)d_in[0];
    const float* targets = (const float*)d_in[1];
    float* out = (float*)d_out;

    float* partial = (float*)d_ws;   // 4 KB

    dim3 gM(HW / 16, HW / RPB, 2);
    k_main<<<gM, 256, 0, stream>>>(preds, targets, partial);

    k_fin<<<1, 256, 0, stream>>>(partial, out);
}